// Round 2
// baseline (238.031 us; speedup 1.0000x reference)
//
#include <hip/hip_runtime.h>

// PCEN: M_t = (1-s) M_{t-1} + s x_t (IIR along T, T=2048 contiguous per row),
// out = (x*(eps+M)^-alpha + bias)^power - bias^power.
// One wave per row. Coalesced float4 global <-> padded LDS transpose,
// lane-local scan of 32 elems + Kogge-Stone wave scan of affine carries.
// Transcendentals via __builtin_amdgcn_{exp2f,logf} (v_exp_f32 / v_log_f32,
// both base-2) — the __exp2f/__log2f spellings collide with glibc math.h.

#define T_LEN      2048
#define PAD_STRIDE 33          // 32 + 1 pad: scan-read bank = (lane+j)%32 -> 2-way (free)
#define LDS_ROW    (64 * PAD_STRIDE)

__device__ __forceinline__ float fast_exp2(float x) { return __builtin_amdgcn_exp2f(x); }
__device__ __forceinline__ float fast_log2(float x) { return __builtin_amdgcn_logf(x); }

__global__ __launch_bounds__(256) void pcen_kernel(
    const float* __restrict__ x,
    const float* __restrict__ alpha_p,
    const float* __restrict__ power_p,
    const float* __restrict__ bias_p,
    float* __restrict__ out)
{
    __shared__ float lds[4][LDS_ROW];   // 33,792 B/block -> 4 blocks/CU

    const int wave = threadIdx.x >> 6;
    const int lane = threadIdx.x & 63;
    const int row  = (blockIdx.x << 2) | wave;

    const float alpha = alpha_p[0];
    const float power = power_p[0];
    const float bias  = bias_p[0];

    const float A = 0.985f;   // 1 - SMOOTH
    const float S = 0.015f;   // SMOOTH

    const float* xr  = x   + (size_t)row * T_LEN;
    float*       orw = out + (size_t)row * T_LEN;
    float*       L   = lds[wave];

    // ---- coalesced global -> padded LDS (lane i: float4 at elem 4i + 256k) ----
#pragma unroll
    for (int k = 0; k < 8; ++k) {
        const int e = 4 * lane + 256 * k;                 // 4-group never crosses a 32-seg
        const float4 v = *reinterpret_cast<const float4*>(xr + e);
        const int idx = ((e >> 5) * PAD_STRIDE) + (e & 31);
        L[idx + 0] = v.x; L[idx + 1] = v.y; L[idx + 2] = v.z; L[idx + 3] = v.w;
    }
    __syncthreads();

    // ---- lane-local scan of 32 consecutive elements (zero initial state) ----
    float xv[32], mv[32];
    const int base = lane * PAD_STRIDE;
    float m = 0.0f;
#pragma unroll
    for (int j = 0; j < 32; ++j) {
        const float xx = L[base + j];
        xv[j] = xx;
        m = A * m + S * xx;
        mv[j] = m;
    }

    // ---- wave-level inclusive scan of segment end-states ----
    // combine: S_i = m_end_i + f * S_{i-1}, f = A^32; Kogge-Stone multiplier at
    // offset d is f^d (same for all participating lanes).
    float f = A; f *= f; f *= f; f *= f; f *= f; f *= f;  // A^32
    float s = m;
    float g = f;
#pragma unroll
    for (int d = 1; d < 64; d <<= 1) {
        const float so = __shfl_up(s, d, 64);
        if (lane >= d) s += g * so;
        g *= g;
    }
    float carry = __shfl_up(s, 1, 64);   // exclusive: M at element (32*lane - 1)
    if (lane == 0) carry = 0.0f;

    // ---- apply carry + epilogue; write results back into LDS ----
    const float bias_pow = fast_exp2(power * fast_log2(bias));
    float pa = A * carry;                // A^(j+1) * carry, incrementally
#pragma unroll
    for (int j = 0; j < 32; ++j) {
        const float M   = mv[j] + pa;
        pa *= A;
        const float den = 1e-9f + M;
        const float t   = xv[j] * fast_exp2(-alpha * fast_log2(den)) + bias;
        const float r   = fast_exp2(power * fast_log2(t)) - bias_pow;
        L[base + j] = r;
    }
    __syncthreads();

    // ---- padded LDS -> coalesced global store ----
#pragma unroll
    for (int k = 0; k < 8; ++k) {
        const int e   = 4 * lane + 256 * k;
        const int idx = ((e >> 5) * PAD_STRIDE) + (e & 31);
        float4 v;
        v.x = L[idx + 0]; v.y = L[idx + 1]; v.z = L[idx + 2]; v.w = L[idx + 3];
        *reinterpret_cast<float4*>(orw + e) = v;
    }
}

extern "C" void kernel_launch(void* const* d_in, const int* in_sizes, int n_in,
                              void* d_out, int out_size, void* d_ws, size_t ws_size,
                              hipStream_t stream) {
    const float* x       = (const float*)d_in[0];
    const float* alpha_p = (const float*)d_in[1];
    const float* power_p = (const float*)d_in[2];
    const float* bias_p  = (const float*)d_in[3];
    float* out           = (float*)d_out;

    const int nrows  = in_sizes[0] / T_LEN;   // 16384, divisible by 4
    const int blocks = nrows / 4;

    pcen_kernel<<<blocks, 256, 0, stream>>>(x, alpha_p, power_p, bias_p, out);
}